// Round 1
// baseline (1755.079 us; speedup 1.0000x reference)
//
#include <hip/hip_runtime.h>

#define B 8
#define CIN 64
#define COUT 128
#define H 256
#define W 256
#define HW 65536
#define OH 128
#define OW 128

// CDF 9/7 analysis filters
__constant__ float c_h0[9] = {0.026748757410810f, -0.016864118442875f, -0.078223266528990f,
                              0.266864118442875f, 0.602949018236360f, 0.266864118442875f,
                              -0.078223266528990f, -0.016864118442875f, 0.026748757410810f};
__constant__ float c_h1[7] = {0.091271763114250f, -0.057543526228500f, -0.591271763114250f,
                              1.115087052457000f, -0.591271763114250f, -0.057543526228500f,
                              0.091271763114250f};

__device__ __forceinline__ unsigned short f2bf(float f) {
    unsigned int x = __float_as_uint(f);
    unsigned int r = (x + 0x7fffu + ((x >> 16) & 1u)) >> 16;  // RNE, inputs are finite
    return (unsigned short)r;
}
__device__ __forceinline__ float bf2f(unsigned short h) {
    return __uint_as_float(((unsigned int)h) << 16);
}
__device__ __forceinline__ int refl(int i) {
    if (i < 0) return -i;
    if (i > 255) return 510 - i;
    return i;
}

// ---------------------------------------------------------------- sigma
// one power iteration with fixed u: v = W^T u; v /= ||v||; sigma = ||W v||
__global__ void sigma_kernel(const float* __restrict__ w, const float* __restrict__ u,
                             float* __restrict__ inv_sigma) {
    __shared__ float v[576];
    __shared__ float red[256];
    const int tid = threadIdx.x;
    for (int j = tid; j < 576; j += 256) {
        float s = 0.f;
        for (int o = 0; o < 128; ++o) s += w[o * 576 + j] * u[o];
        v[j] = s;
    }
    __syncthreads();
    float s = 0.f;
    for (int j = tid; j < 576; j += 256) s += v[j] * v[j];
    red[tid] = s;
    __syncthreads();
    for (int off = 128; off > 0; off >>= 1) {
        if (tid < off) red[tid] += red[tid + off];
        __syncthreads();
    }
    const float vn = sqrtf(red[0]) + 1e-12f;
    __syncthreads();
    float tacc = 0.f;
    if (tid < 128) {
        float d = 0.f;
        for (int j = 0; j < 576; ++j) d += w[tid * 576 + j] * v[j];
        d /= vn;
        tacc = d * d;
    }
    red[tid] = tacc;
    __syncthreads();
    for (int off = 128; off > 0; off >>= 1) {
        if (tid < off) red[tid] += red[tid + off];
        __syncthreads();
    }
    if (tid == 0) inv_sigma[0] = 1.f / sqrtf(red[0]);
}

// ---------------------------------------------------------------- prep
// wt[(c*9+kh*3+kw)*128 + o] = w_sn ;  gamma_t[c*128+o] = gamma[o*128+c]
__global__ void prep_kernel(const float* __restrict__ w, const float* __restrict__ gamma,
                            const float* __restrict__ inv_sigma,
                            float* __restrict__ wt, float* __restrict__ gamma_t) {
    const int i = blockIdx.x * 256 + threadIdx.x;
    if (i < 73728) {
        const int o = i / 576, r = i - o * 576;
        wt[r * 128 + o] = w[i] * inv_sigma[0];
    } else if (i < 90112) {
        const int j = i - 73728;
        const int o = j >> 7, c = j & 127;
        gamma_t[c * 128 + o] = gamma[j];
    }
}

// ---------------------------------------------------------------- conv3x3 + partial renorm
// block: 256 thr = 16 tx (w-groups of 4px) x 4 hy x 4 og (8 oc each)
// tile: 64w x 4h x 32oc.  grid: (4 wtiles, 64 htiles, 8b*4octiles)
__global__ void conv_kernel(const float* __restrict__ x, const float* __restrict__ mask,
                            const float* __restrict__ wt, const float* __restrict__ bias,
                            unsigned short* __restrict__ t, float* __restrict__ valid) {
    __shared__ float mt[6][66];
    __shared__ float xs[8][6][66];
    __shared__ float wsm[8 * 3 * 3 * 32];

    const int tid = threadIdx.x;
    const int tx = tid & 15, hy = (tid >> 4) & 3, og = tid >> 6;
    const int b = blockIdx.z >> 2;
    const int ot = blockIdx.z & 3;
    const int oc0 = ot * 32 + og * 8;
    const int h0 = blockIdx.y * 4;
    const int wc0 = blockIdx.x * 64;
    const int h = h0 + hy;
    const int w0 = wc0 + tx * 4;

    for (int i = tid; i < 396; i += 256) {
        const int r = i / 66, cw = i - r * 66;
        const int hr = h0 - 1 + r, wc = wc0 - 1 + cw;
        float mval = 0.f;
        if (hr >= 0 && hr < H && wc >= 0 && wc < W) mval = mask[b * HW + hr * W + wc];
        mt[r][cw] = mval;
    }
    __syncthreads();

    float acc[4][8];
#pragma unroll
    for (int p = 0; p < 4; ++p)
#pragma unroll
        for (int j = 0; j < 8; ++j) acc[p][j] = 0.f;

    for (int cb = 0; cb < 8; ++cb) {
        for (int i = tid; i < 3168; i += 256) {
            const int ci = i / 396;
            const int rem = i - ci * 396;
            const int r = rem / 66, cw = rem - r * 66;
            const int hr = h0 - 1 + r, wc = wc0 - 1 + cw;
            float val = 0.f;
            if (hr >= 0 && hr < H && wc >= 0 && wc < W)
                val = x[((b * CIN + cb * 8 + ci) * H + hr) * W + wc] * mt[r][cw];
            xs[ci][r][cw] = val;
        }
        for (int i = tid; i < 2304; i += 256) {
            const int rr = i >> 5, oj = i & 31;
            wsm[i] = wt[(cb * 72 + rr) * 128 + ot * 32 + oj];
        }
        __syncthreads();
#pragma unroll
        for (int ci = 0; ci < 8; ++ci) {
#pragma unroll
            for (int kh = 0; kh < 3; ++kh) {
                float xr[6];
#pragma unroll
                for (int ii = 0; ii < 6; ++ii) xr[ii] = xs[ci][hy + kh][tx * 4 + ii];
#pragma unroll
                for (int kw = 0; kw < 3; ++kw) {
                    const float4 wa = *(const float4*)&wsm[(ci * 9 + kh * 3 + kw) * 32 + og * 8];
                    const float4 wb = *(const float4*)&wsm[(ci * 9 + kh * 3 + kw) * 32 + og * 8 + 4];
#pragma unroll
                    for (int p = 0; p < 4; ++p) {
                        const float xv = xr[kw + p];
                        acc[p][0] += xv * wa.x; acc[p][1] += xv * wa.y;
                        acc[p][2] += xv * wa.z; acc[p][3] += xv * wa.w;
                        acc[p][4] += xv * wb.x; acc[p][5] += xv * wb.y;
                        acc[p][6] += xv * wb.z; acc[p][7] += xv * wb.w;
                    }
                }
            }
        }
        __syncthreads();
    }

    float bs[8];
#pragma unroll
    for (int j = 0; j < 8; ++j) bs[j] = bias[oc0 + j];

    float msv[4], ratio[4];
#pragma unroll
    for (int p = 0; p < 4; ++p) {
        float ms = 0.f;
#pragma unroll
        for (int kh = 0; kh < 3; ++kh)
#pragma unroll
            for (int kw = 0; kw < 3; ++kw) ms += mt[hy + kh][tx * 4 + p + kw];
        msv[p] = ms;
        ratio[p] = (ms > 0.f) ? 9.f / fmaxf(ms, 1e-8f) : 0.f;
    }
#pragma unroll
    for (int j = 0; j < 8; ++j) {
        uint2 pk;
        float v0 = (msv[0] > 0.f) ? acc[0][j] * ratio[0] + bs[j] : 0.f;
        float v1 = (msv[1] > 0.f) ? acc[1][j] * ratio[1] + bs[j] : 0.f;
        float v2 = (msv[2] > 0.f) ? acc[2][j] * ratio[2] + bs[j] : 0.f;
        float v3 = (msv[3] > 0.f) ? acc[3][j] * ratio[3] + bs[j] : 0.f;
        pk.x = (unsigned int)f2bf(v0) | ((unsigned int)f2bf(v1) << 16);
        pk.y = (unsigned int)f2bf(v2) | ((unsigned int)f2bf(v3) << 16);
        *(uint2*)&t[((b * COUT + oc0 + j) * H + h) * W + w0] = pk;
    }
    if (ot == 0 && og == 0) {
        float4 vv;
        vv.x = msv[0] > 0.f ? 1.f : 0.f;
        vv.y = msv[1] > 0.f ? 1.f : 0.f;
        vv.z = msv[2] > 0.f ? 1.f : 0.f;
        vv.w = msv[3] > 0.f ? 1.f : 0.f;
        *(float4*)&valid[b * HW + h * W + w0] = vv;
    }
}

// ---------------------------------------------------------------- GDN (in-place on t)
// block: 64 pixels x all 128 channels; thread: 32 o-strip for one pixel
__global__ void gdn_kernel(unsigned short* __restrict__ t, const float* __restrict__ gamma_t,
                           const float* __restrict__ beta, const float* __restrict__ valid) {
    __shared__ float ts[128][64];
    const int tid = threadIdx.x;
    const int b = blockIdx.x >> 10;
    const int p0 = (blockIdx.x & 1023) << 6;

    for (int i = tid; i < 8192; i += 256) {
        const int c = i >> 6, px = i & 63;
        ts[c][px] = bf2f(t[(b * COUT + c) * HW + p0 + px]);
    }
    __syncthreads();

    const int px = tid & 63;
    const int obase = __builtin_amdgcn_readfirstlane((tid >> 6) << 5);
    float acc[32];
#pragma unroll
    for (int j = 0; j < 32; ++j) acc[j] = 0.f;

#pragma unroll 2
    for (int c = 0; c < 128; ++c) {
        const float xv = ts[c][px];
        const float x2 = xv * xv;
        const float* g = &gamma_t[c * 128 + obase];
#pragma unroll
        for (int j = 0; j < 32; j += 4) {
            const float4 gv = *(const float4*)&g[j];
            acc[j]     += gv.x * x2;
            acc[j + 1] += gv.y * x2;
            acc[j + 2] += gv.z * x2;
            acc[j + 3] += gv.w * x2;
        }
    }

    const float vv = valid[b * HW + p0 + px];
#pragma unroll
    for (int j = 0; j < 32; ++j) {
        const int o = obase + j;
        const float d = beta[o] + acc[j];
        const float y = ts[o][px] * rsqrtf(d) * vv;
        t[(b * COUT + o) * HW + p0 + px] = f2bf(y);
    }
}

// ---------------------------------------------------------------- fused DWT (4 subbands)
// block per (b*c, 16x32 output tile): y tile 40x72 -> row filt -> col filt
__global__ void dwt_kernel(const unsigned short* __restrict__ y, float* __restrict__ out) {
    __shared__ float ys[40][72];
    __shared__ float lo[16][72];
    __shared__ float hi[16][72];
    const int tid = threadIdx.x;
    const int wt_ = blockIdx.x & 3;
    const int ht_ = blockIdx.x >> 2;
    const int bc = blockIdx.y;
    const int ho0 = ht_ * 16, wo0 = wt_ * 32;
    const int r0 = 2 * ho0 - 4, c0 = 2 * wo0 - 4;
    const unsigned short* yb = y + bc * HW;

    for (int i = tid; i < 2880; i += 256) {
        const int lr = i / 72, lc = i - lr * 72;
        const int gr = refl(r0 + lr), gc = refl(c0 + lc);
        ys[lr][lc] = bf2f(yb[gr * W + gc]);
    }
    __syncthreads();

    for (int i = tid; i < 1152; i += 256) {
        const int r = i / 72, cc = i - r * 72;
        float sl = 0.f, sh = 0.f;
#pragma unroll
        for (int k = 0; k < 9; ++k) sl += c_h0[k] * ys[2 * r + k][cc];
#pragma unroll
        for (int k = 0; k < 7; ++k) sh += c_h1[k] * ys[2 * r + 1 + k][cc];
        lo[r][cc] = sl;
        hi[r][cc] = sh;
    }
    __syncthreads();

    const int j = tid & 31;
    const int rb = tid >> 5;
    float* o_ll = out;
    float* o_lh = out + 16908288;
    float* o_hl = out + 33685504;
    float* o_hh = out + 50462720;
#pragma unroll
    for (int rr = rb; rr < 16; rr += 8) {
        float ll = 0.f, lh = 0.f, hl = 0.f, hh = 0.f;
#pragma unroll
        for (int k = 0; k < 9; ++k) {
            ll += c_h0[k] * lo[rr][2 * j + k];
            hl += c_h0[k] * hi[rr][2 * j + k];
        }
#pragma unroll
        for (int k = 0; k < 7; ++k) {
            lh += c_h1[k] * lo[rr][2 * j + 1 + k];
            hh += c_h1[k] * hi[rr][2 * j + 1 + k];
        }
        const int idx = (bc * OH + ho0 + rr) * OW + wo0 + j;
        o_ll[idx] = ll; o_lh[idx] = lh; o_hl[idx] = hl; o_hh[idx] = hh;
    }
}

// ---------------------------------------------------------------- DWT masks
__global__ void dwtmask_kernel(const float* __restrict__ valid, float* __restrict__ out) {
    const int g = blockIdx.x * 256 + threadIdx.x;  // 0..131071
    const int b = g >> 14;
    const int rem = g & 16383;
    const int i = rem >> 7, j = rem & 127;
    const float* vb = valid + b * HW;
    bool bll = false, blh = false, bhl = false, bhh = false;
    for (int k1 = 0; k1 < 9; ++k1) {
        const int rr = refl(2 * i - 4 + k1);
        const bool in7r = (k1 >= 1 && k1 <= 7);
        for (int k2 = 0; k2 < 9; ++k2) {
            const int cc = refl(2 * j - 4 + k2);
            if (vb[rr * W + cc] > 0.f) {
                const bool in7c = (k2 >= 1 && k2 <= 7);
                bll = true;
                blh |= in7c;
                bhl |= in7r;
                bhh |= (in7r && in7c);
            }
        }
    }
    out[16777216 + g] = bll ? 1.f : 0.f;  // m_ll
    out[67239936 + g] = blh ? 1.f : 0.f;  // m_lh
    out[67371008 + g] = bhl ? 1.f : 0.f;  // m_hl
    out[67502080 + g] = bhh ? 1.f : 0.f;  // m_hh
}

// ---------------------------------------------------------------- launch
extern "C" void kernel_launch(void* const* d_in, const int* in_sizes, int n_in,
                              void* d_out, int out_size, void* d_ws, size_t ws_size,
                              hipStream_t stream) {
    const float* x     = (const float*)d_in[0];
    const float* mask  = (const float*)d_in[1];
    const float* w     = (const float*)d_in[2];
    const float* bias  = (const float*)d_in[3];
    const float* u     = (const float*)d_in[4];
    const float* beta  = (const float*)d_in[5];
    const float* gamma = (const float*)d_in[6];
    float* out = (float*)d_out;

    float* f_ws = (float*)d_ws;
    float* inv_sigma = f_ws;                       // 1 float (pad to 256)
    float* wt        = f_ws + 256;                 // 73728 floats, [c*9+kh*3+kw][o]
    float* gamma_t   = wt + 73728;                 // 16384 floats, [c][o]
    float* valid     = gamma_t + 16384;            // 524288 floats [b][h][w]
    unsigned short* t = (unsigned short*)(valid + 524288);  // bf16 [b][o][h][w], 128 MiB

    sigma_kernel<<<1, 256, 0, stream>>>(w, u, inv_sigma);
    prep_kernel<<<352, 256, 0, stream>>>(w, gamma, inv_sigma, wt, gamma_t);
    conv_kernel<<<dim3(4, 64, 32), 256, 0, stream>>>(x, mask, wt, bias, t, valid);
    gdn_kernel<<<8192, 256, 0, stream>>>(t, gamma_t, beta, valid);
    dwt_kernel<<<dim3(32, 1024), 256, 0, stream>>>(t, out);
    dwtmask_kernel<<<512, 256, 0, stream>>>(valid, out);
}

// Round 2
// 917.738 us; speedup vs baseline: 1.9124x; 1.9124x over previous
//
#include <hip/hip_runtime.h>

#define B 8
#define CIN 64
#define COUT 128
#define H 256
#define W 256
#define HW 65536
#define OH 128
#define OW 128

typedef __attribute__((ext_vector_type(8))) short bf16x8;
typedef __attribute__((ext_vector_type(16))) float f32x16;

// CDF 9/7 analysis filters
__constant__ float c_h0[9] = {0.026748757410810f, -0.016864118442875f, -0.078223266528990f,
                              0.266864118442875f, 0.602949018236360f, 0.266864118442875f,
                              -0.078223266528990f, -0.016864118442875f, 0.026748757410810f};
__constant__ float c_h1[7] = {0.091271763114250f, -0.057543526228500f, -0.591271763114250f,
                              1.115087052457000f, -0.591271763114250f, -0.057543526228500f,
                              0.091271763114250f};

__device__ __forceinline__ unsigned short f2bf(float f) {
    unsigned int x = __float_as_uint(f);
    unsigned int r = (x + 0x7fffu + ((x >> 16) & 1u)) >> 16;  // RNE, inputs finite
    return (unsigned short)r;
}
__device__ __forceinline__ float bf2f(unsigned short h) {
    return __uint_as_float(((unsigned int)h) << 16);
}
__device__ __forceinline__ int refl(int i) {
    if (i < 0) return -i;
    if (i > 255) return 510 - i;
    return i;
}

// ---------------------------------------------------------------- sigma
__global__ void sigma_kernel(const float* __restrict__ w, const float* __restrict__ u,
                             float* __restrict__ inv_sigma) {
    __shared__ float v[576];
    __shared__ float red[256];
    const int tid = threadIdx.x;
    for (int j = tid; j < 576; j += 256) {
        float s = 0.f;
        for (int o = 0; o < 128; ++o) s += w[o * 576 + j] * u[o];
        v[j] = s;
    }
    __syncthreads();
    float s = 0.f;
    for (int j = tid; j < 576; j += 256) s += v[j] * v[j];
    red[tid] = s;
    __syncthreads();
    for (int off = 128; off > 0; off >>= 1) {
        if (tid < off) red[tid] += red[tid + off];
        __syncthreads();
    }
    const float vn = sqrtf(red[0]) + 1e-12f;
    __syncthreads();
    float tacc = 0.f;
    if (tid < 128) {
        float d = 0.f;
        for (int j = 0; j < 576; ++j) d += w[tid * 576 + j] * v[j];
        d /= vn;
        tacc = d * d;
    }
    red[tid] = tacc;
    __syncthreads();
    for (int off = 128; off > 0; off >>= 1) {
        if (tid < off) red[tid] += red[tid + off];
        __syncthreads();
    }
    if (tid == 0) inv_sigma[0] = 1.f / sqrtf(red[0]);
}

// ---------------------------------------------------------------- prep
// wt_bf[(o*9+tap)*64 + c] = bf16(w_sn[o][c][tap]); gamma_bf[o*128+c] = bf16(gamma)
__global__ void prep_kernel(const float* __restrict__ w, const float* __restrict__ gamma,
                            const float* __restrict__ inv_sigma,
                            unsigned short* __restrict__ wt_bf,
                            unsigned short* __restrict__ gamma_bf) {
    const int i = blockIdx.x * 256 + threadIdx.x;
    const float is = inv_sigma[0];
    if (i < 73728) {
        const int o = i / 576, rem = i - o * 576;
        const int c = rem / 9, tap = rem - c * 9;
        wt_bf[(o * 9 + tap) * 64 + c] = f2bf(w[i] * is);
    } else if (i < 90112) {
        const int j = i - 73728;
        gamma_bf[j] = f2bf(gamma[j]);
    }
}

// ---------------------------------------------------------------- fused conv3x3 + partial renorm + GDN (MFMA)
// block: 256 thr = 4 waves. tile: 4 rows x 32 px, all 128 oc.
// wave w owns oc-tile n0=w*32; M-tiles = 4 image rows.
__global__ __launch_bounds__(256, 2) void convgdn_kernel(
    const float* __restrict__ x, const float* __restrict__ mask,
    const unsigned short* __restrict__ wt_bf, const float* __restrict__ bias,
    const unsigned short* __restrict__ gamma_bf, const float* __restrict__ beta,
    unsigned short* __restrict__ t, float* __restrict__ valid) {
    // LDS: region1 = max(raw 26112, ygdn 33792) | y2 34816 | mask 816 | ratio 512
    __shared__ __align__(16) char lds[69936];
    unsigned short* raw  = (unsigned short*)lds;            // [6][8cblk][34col][8c]
    unsigned short* ygdn = (unsigned short*)lds;            // [128oc][132]
    unsigned short* y2   = (unsigned short*)(lds + 33792);  // [128px][136]
    float* mlds = (float*)(lds + 68608);                    // [6][34]
    float* rlds = (float*)(lds + 69424);                    // [128] ratio (0 if invalid)

    const int tid = threadIdx.x;
    const int lane = tid & 63;
    const int lo = lane & 31;
    const int hi = lane >> 5;
    const int n0 = (tid >> 6) << 5;
    const int oc = n0 + lo;  // this lane's output channel (all tiles)
    const int b = blockIdx.z;
    const int h0 = blockIdx.y << 2;
    const int wc0 = blockIdx.x << 5;

    // stage mask tile [6][34] (zero-pad outside image)
    if (tid < 204) {
        const int r = tid / 34, cl = tid - r * 34;
        const int hr = h0 - 1 + r, wc = wc0 - 1 + cl;
        float mv = 0.f;
        if (hr >= 0 && hr < H && wc >= 0 && wc < W) mv = mask[b * HW + hr * W + wc];
        mlds[tid] = mv;
    }
    __syncthreads();

    // stage xm = x*mask as bf16 into raw[r][c>>3][col][c&7]; compute ratio
    for (int i = tid; i < 13056; i += 256) {
        const int c = i / 204, rem = i - c * 204;
        const int r = rem / 34, cl = rem - r * 34;
        const int hr = h0 - 1 + r, wc = wc0 - 1 + cl;
        float v = 0.f;
        if (hr >= 0 && hr < H && wc >= 0 && wc < W)
            v = x[((b * CIN + c) * H + hr) * W + wc] * mlds[r * 34 + cl];
        raw[((r * 8 + (c >> 3)) * 34 + cl) * 8 + (c & 7)] = f2bf(v);
    }
    if (tid < 128) {
        const int mt = tid >> 5, cl = tid & 31;
        float ms = 0.f;
#pragma unroll
        for (int a = 0; a < 3; ++a)
#pragma unroll
            for (int bb = 0; bb < 3; ++bb) ms += mlds[(mt + a) * 34 + cl + bb];
        const bool vld = ms > 0.f;
        rlds[tid] = vld ? 9.f / fmaxf(ms, 1e-8f) : 0.f;
        valid[b * HW + (h0 + mt) * W + wc0 + cl] = vld ? 1.f : 0.f;
    }
    __syncthreads();

    // ---- conv implicit GEMM: K = 9 taps x 64 c (tap-major, c-fastest), 36 chunks of 16
    f32x16 acc[4];
#pragma unroll
    for (int mt = 0; mt < 4; ++mt)
#pragma unroll
        for (int r = 0; r < 16; ++r) acc[mt][r] = 0.f;

    for (int chunk = 0; chunk < 36; ++chunk) {
        const int tap = chunk >> 2;
        const int cc = chunk & 3;
        const int c0 = cc * 16 + hi * 8;
        const int kh = tap / 3, kw = tap - kh * 3;
        const bf16x8 bfrag = *(const bf16x8*)&wt_bf[(oc * 9 + tap) * 64 + c0];
#pragma unroll
        for (int mt = 0; mt < 4; ++mt) {
            const bf16x8 afrag =
                *(const bf16x8*)&raw[(((mt + kh) * 8 + (c0 >> 3)) * 34 + (lo + kw)) * 8];
            acc[mt] = __builtin_amdgcn_mfma_f32_32x32x16_bf16(afrag, bfrag, acc[mt], 0, 0, 0);
        }
    }

    // ---- epilogue: y = valid ? acc*ratio + bias : 0 ; write y^2 (bf16) to y2[px][c]
    const float bs = bias[oc];
    const float bt = beta[oc];
#pragma unroll
    for (int mt = 0; mt < 4; ++mt) {
#pragma unroll
        for (int r = 0; r < 16; ++r) {
            const int rowq = (r & 3) + 8 * (r >> 2) + 4 * hi;  // pixel col within tile
            const float rat = rlds[mt * 32 + rowq];
            const float y = (rat > 0.f) ? acc[mt][r] * rat + bs : 0.f;
            acc[mt][r] = y;  // keep y in regs
            y2[(mt * 32 + rowq) * 136 + oc] = f2bf(y * y);
        }
    }
    __syncthreads();

    // ---- GDN MFMA: denom_acc[px][o] = sum_c gamma[o][c] * y2[px][c], K=128 in 8 chunks
    f32x16 acc2[4];
#pragma unroll
    for (int g = 0; g < 4; ++g)
#pragma unroll
        for (int r = 0; r < 16; ++r) acc2[g][r] = 0.f;

    for (int ch = 0; ch < 8; ++ch) {
        const int c0 = ch * 16 + hi * 8;
        const bf16x8 gb = *(const bf16x8*)&gamma_bf[oc * 128 + c0];
#pragma unroll
        for (int g = 0; g < 4; ++g) {
            const bf16x8 ga = *(const bf16x8*)&y2[(g * 32 + lo) * 136 + c0];
            acc2[g] = __builtin_amdgcn_mfma_f32_32x32x16_bf16(ga, gb, acc2[g], 0, 0, 0);
        }
    }

    // ---- final: y_gdn = y * rsqrt(beta + denom); write to ygdn[oc][px] (LDS transpose)
#pragma unroll
    for (int mt = 0; mt < 4; ++mt) {
#pragma unroll
        for (int rg = 0; rg < 4; ++rg) {
            const int base = 8 * rg + 4 * hi;
            ushort4 pk;
            unsigned short* pp = (unsigned short*)&pk;
#pragma unroll
            for (int j = 0; j < 4; ++j) {
                const int r = rg * 4 + j;
                const float d = bt + acc2[mt][r];
                pp[j] = f2bf(acc[mt][r] * rsqrtf(d));
            }
            *(ushort4*)&ygdn[oc * 132 + mt * 32 + base] = pk;
        }
    }
    __syncthreads();

    // ---- coalesced dump: each thread writes one 64-B row-run (32 px) of one oc
#pragma unroll
    for (int it = 0; it < 2; ++it) {
        const int idx = it * 256 + tid;
        const int oc2 = idx >> 2, mt2 = idx & 3;
        const unsigned short* src = &ygdn[oc2 * 132 + mt2 * 32];
        unsigned short* dst = &t[((b * COUT + oc2) * H + h0 + mt2) * W + wc0];
#pragma unroll
        for (int k = 0; k < 8; ++k)
            *(ushort4*)(dst + k * 4) = *(const ushort4*)(src + k * 4);
    }
}

// ---------------------------------------------------------------- fused DWT (4 subbands)
__global__ void dwt_kernel(const unsigned short* __restrict__ y, float* __restrict__ out) {
    __shared__ float ys[40][72];
    __shared__ float lo[16][72];
    __shared__ float hi[16][72];
    const int tid = threadIdx.x;
    const int wt_ = blockIdx.x & 3;
    const int ht_ = blockIdx.x >> 2;
    const int bc = blockIdx.y;
    const int ho0 = ht_ * 16, wo0 = wt_ * 32;
    const int r0 = 2 * ho0 - 4, c0 = 2 * wo0 - 4;
    const unsigned short* yb = y + bc * HW;

    for (int i = tid; i < 2880; i += 256) {
        const int lr = i / 72, lc = i - lr * 72;
        const int gr = refl(r0 + lr), gc = refl(c0 + lc);
        ys[lr][lc] = bf2f(yb[gr * W + gc]);
    }
    __syncthreads();

    for (int i = tid; i < 1152; i += 256) {
        const int r = i / 72, cc = i - r * 72;
        float sl = 0.f, sh = 0.f;
#pragma unroll
        for (int k = 0; k < 9; ++k) sl += c_h0[k] * ys[2 * r + k][cc];
#pragma unroll
        for (int k = 0; k < 7; ++k) sh += c_h1[k] * ys[2 * r + 1 + k][cc];
        lo[r][cc] = sl;
        hi[r][cc] = sh;
    }
    __syncthreads();

    const int j = tid & 31;
    const int rb = tid >> 5;
    float* o_ll = out;
    float* o_lh = out + 16908288;
    float* o_hl = out + 33685504;
    float* o_hh = out + 50462720;
#pragma unroll
    for (int rr = rb; rr < 16; rr += 8) {
        float ll = 0.f, lh = 0.f, hl = 0.f, hh = 0.f;
#pragma unroll
        for (int k = 0; k < 9; ++k) {
            ll += c_h0[k] * lo[rr][2 * j + k];
            hl += c_h0[k] * hi[rr][2 * j + k];
        }
#pragma unroll
        for (int k = 0; k < 7; ++k) {
            lh += c_h1[k] * lo[rr][2 * j + 1 + k];
            hh += c_h1[k] * hi[rr][2 * j + 1 + k];
        }
        const int idx = (bc * OH + ho0 + rr) * OW + wo0 + j;
        o_ll[idx] = ll; o_lh[idx] = lh; o_hl[idx] = hl; o_hh[idx] = hh;
    }
}

// ---------------------------------------------------------------- DWT masks
__global__ void dwtmask_kernel(const float* __restrict__ valid, float* __restrict__ out) {
    const int g = blockIdx.x * 256 + threadIdx.x;  // 0..131071
    const int b = g >> 14;
    const int rem = g & 16383;
    const int i = rem >> 7, j = rem & 127;
    const float* vb = valid + b * HW;
    bool bll = false, blh = false, bhl = false, bhh = false;
    for (int k1 = 0; k1 < 9; ++k1) {
        const int rr = refl(2 * i - 4 + k1);
        const bool in7r = (k1 >= 1 && k1 <= 7);
        for (int k2 = 0; k2 < 9; ++k2) {
            const int cc = refl(2 * j - 4 + k2);
            if (vb[rr * W + cc] > 0.f) {
                const bool in7c = (k2 >= 1 && k2 <= 7);
                bll = true;
                blh |= in7c;
                bhl |= in7r;
                bhh |= (in7r && in7c);
            }
        }
    }
    out[16777216 + g] = bll ? 1.f : 0.f;  // m_ll
    out[67239936 + g] = blh ? 1.f : 0.f;  // m_lh
    out[67371008 + g] = bhl ? 1.f : 0.f;  // m_hl
    out[67502080 + g] = bhh ? 1.f : 0.f;  // m_hh
}

// ---------------------------------------------------------------- launch
extern "C" void kernel_launch(void* const* d_in, const int* in_sizes, int n_in,
                              void* d_out, int out_size, void* d_ws, size_t ws_size,
                              hipStream_t stream) {
    const float* x     = (const float*)d_in[0];
    const float* mask  = (const float*)d_in[1];
    const float* w     = (const float*)d_in[2];
    const float* bias  = (const float*)d_in[3];
    const float* u     = (const float*)d_in[4];
    const float* beta  = (const float*)d_in[5];
    const float* gamma = (const float*)d_in[6];
    float* out = (float*)d_out;

    float* f_ws = (float*)d_ws;
    float* inv_sigma = f_ws;                                   // 256 floats
    unsigned short* wt_bf    = (unsigned short*)(f_ws + 256);  // 73728 bf16 [o][tap][c]
    unsigned short* gamma_bf = wt_bf + 73728;                  // 16384 bf16 [o][c]
    float* valid = (float*)(gamma_bf + 16384);                 // 524288 fp32 [b][h][w]
    unsigned short* t = (unsigned short*)(valid + 524288);     // bf16 [b][o][h][w]

    sigma_kernel<<<1, 256, 0, stream>>>(w, u, inv_sigma);
    prep_kernel<<<352, 256, 0, stream>>>(w, gamma, inv_sigma, wt_bf, gamma_bf);
    convgdn_kernel<<<dim3(8, 64, 8), 256, 0, stream>>>(x, mask, wt_bf, bias, gamma_bf, beta,
                                                       t, valid);
    dwt_kernel<<<dim3(32, 1024), 256, 0, stream>>>(t, out);
    dwtmask_kernel<<<512, 256, 0, stream>>>(valid, out);
}